// Round 4
// baseline (513.656 us; speedup 1.0000x reference)
//
#include <hip/hip_runtime.h>

#define KCODES 512
#define DIM 64
#define NB 32
#define NH 64
#define NW 64
#define NPTS (NB*NH*NW)     // 131072
#define HW (NH*NW)          // 4096

// ---- output layout (floats) ----
#define O_OUT  0
#define O_LOSS 8388608
#define O_IDX  8388609
#define O_EMB  8519681
#define O_M    8552449
#define O_MM   8585217

// ---- workspace layout (floats) ----
#define W_DM   0                    // K*D segment sums
#define W_CNT  (KCODES*DIM)         // 32768: K counts
#define W_LOSS (W_CNT + KCODES)     // 33280: loss accumulator
#define W_C    (W_LOSS + 1)         // 33281: K codeword sq-norms
#define W_NEWM (W_C + KCODES)       // 33793: K smoothed new_M
#define W_TOTAL (W_NEWM + KCODES)   // 34305 floats ~ 137 KB

__global__ void cnorm_kernel(const float* __restrict__ emb, float* __restrict__ ws) {
    int k = blockIdx.x * blockDim.x + threadIdx.x;
    if (k >= KCODES) return;
    float s = 0.f;
    #pragma unroll
    for (int d = 0; d < DIM; ++d) { float v = emb[k*DIM + d]; s += v*v; }
    ws[W_C + k] = s;
}

// Dist + argmin + quantized-out + loss + idx. NO global atomics here:
// rounds 2/3 showed two different dist implementations both land at ~440us
// -> shared bottleneck was the 8.4M contended global atomicAdds (epilogue).
__global__ __launch_bounds__(256, 2) void assign_kernel(
    const float* __restrict__ enc, const float* __restrict__ emb,
    float* __restrict__ out, const float* __restrict__ ws)
{
    __shared__ float Es[64*64];       // 64 codeword rows, 16 KB
    __shared__ float Cs[64];
    __shared__ float T[4][64][17];    // per-wave gather tile (wave-lockstep use)
    const int t = threadIdx.x;
    const int w = t & 63;                       // lane = W coordinate (coalesced)
    const int wv = t >> 6;                      // wave id 0..3
    const int R = blockIdx.x * 4 + wv;          // (b,h) row index, 0..2047
    const int b = R >> 6, h = R & 63;

    const float* px = enc + (size_t)b * DIM * HW + h * NW + w;
    float x[DIM];
    #pragma unroll
    for (int d = 0; d < DIM; ++d) x[d] = px[(size_t)d * HW];

    // ---- distance phase: bit-identical scores to rounds 1-3 ----
    float best = 3.402823466e38f;
    int bidx = 0;
    for (int kc = 0; kc < KCODES; kc += 64) {
        __syncthreads();
        const float4* esrc = (const float4*)(emb + kc * DIM);
        float4* edst = (float4*)Es;
        #pragma unroll
        for (int q = 0; q < 4; ++q) edst[t + q*256] = esrc[t + q*256];
        if (t < 64) Cs[t] = ws[W_C + kc + t];
        __syncthreads();

        for (int kk = 0; kk < 64; ++kk) {
            const float4* er = (const float4*)(Es + kk*64);   // broadcast reads
            float a0 = 0.f, a1 = 0.f, a2 = 0.f, a3 = 0.f;     // 4 indep FMA chains
            #pragma unroll
            for (int q = 0; q < 16; ++q) {
                float4 e = er[q];
                a0 += x[4*q+0]*e.x; a1 += x[4*q+1]*e.y;
                a2 += x[4*q+2]*e.z; a3 += x[4*q+3]*e.w;
            }
            float score = Cs[kk] - 2.f*((a0+a1)+(a2+a3));
            if (score < best) { best = score; bidx = kc + kk; }  // strict < = first-min
        }
    }

    // ---- epilogue: coalesced quantized gather via per-wave tile, no atomics ----
    float* po = out + O_OUT + (size_t)b * DIM * HW + h * NW + w;
    const int pg = w >> 4;      // which of 4 points this lane serves
    const int dl = w & 15;      // dim-in-chunk
    float lsum = 0.f;

    #pragma unroll
    for (int c = 0; c < 4; ++c) {
        #pragma unroll
        for (int jj = 0; jj < 16; ++jj) {      // 4 points x 16 contiguous dims
            int p = jj*4 + pg;
            int kb = __shfl(bidx, p, 64);
            T[wv][p][dl] = emb[kb*64 + c*16 + dl];   // same-wave lockstep tile
        }
        #pragma unroll
        for (int i = 0; i < 16; ++i) {
            float q = T[wv][w][i];
            po[(size_t)(c*16 + i) * HW] = q;
            float df = q - x[c*16 + i];
            lsum = fmaf(df, df, lsum);
        }
    }

    out[O_IDX + (size_t)R*64 + w] = (float)bidx;

    #pragma unroll
    for (int off = 32; off >= 1; off >>= 1) lsum += __shfl_down(lsum, off, 64);
    if (w == 0) atomicAdd((float*)&ws[W_LOSS], lsum);   // 512 ops total: cheap
}

// Per-block LDS accumulation of dm/counts, then one coalesced 64-lane global
// atomic per nonzero codeword row. Each global address touched <=64 times.
__global__ __launch_bounds__(256, 1) void scatter_kernel(
    const float* __restrict__ enc, const float* __restrict__ out,
    float* __restrict__ ws)
{
    __shared__ float dmL[KCODES][65];   // +1 pad: 4 rows/instr land on distinct banks
    __shared__ float cntL[KCODES];
    __shared__ float T[4][64][17];
    const int t = threadIdx.x;
    const int w = t & 63;
    const int wv = t >> 6;
    const int pg = w >> 4, dl = w & 15;

    float* dmf = &dmL[0][0];
    for (int i = t; i < KCODES*65; i += 256) dmf[i] = 0.f;
    for (int i = t; i < KCODES; i += 256) cntL[i] = 0.f;
    __syncthreads();

    for (int r = 0; r < 8; ++r) {
        const int R = blockIdx.x * 32 + r*4 + wv;    // (b,h) row
        const int b = R >> 6, h = R & 63;
        const float* px = enc + (size_t)b * DIM * HW + h * NW + w;
        float x[DIM];
        #pragma unroll
        for (int d = 0; d < DIM; ++d) x[d] = px[(size_t)d * HW];

        int bidx = (int)out[O_IDX + (size_t)R*64 + w];
        atomicAdd(&cntL[bidx], 1.0f);    // LDS atomic; exact integer counts

        #pragma unroll
        for (int c = 0; c < 4; ++c) {
            #pragma unroll
            for (int i = 0; i < 16; ++i) T[wv][w][i] = x[c*16 + i];
            #pragma unroll
            for (int jj = 0; jj < 16; ++jj) {   // 4 points x 16 dims: lanes with
                int p = jj*4 + pg;              // same codeword hit DIFFERENT dims
                int kb = __shfl(bidx, p, 64);   // -> no same-address serialization
                atomicAdd(&dmL[kb][c*16 + dl], T[wv][p][dl]);
            }
        }
    }
    __syncthreads();

    // flush: wave per 128 rows, lane = dim (one 256B-contiguous atomic per row)
    for (int k = wv*128; k < wv*128 + 128; ++k) {
        float c = cntL[k];
        if (c == 0.f) continue;                  // wave-uniform branch
        atomicAdd(&ws[W_DM + k*64 + w], dmL[k][w]);
        if (w == 0) atomicAdd(&ws[W_CNT + k], c);
    }
}

__global__ void finalizeA(const float* __restrict__ emaM,
                          float* __restrict__ out, float* __restrict__ ws)
{
    __shared__ float red[512];
    int k = threadIdx.x;  // 512 threads, one per codeword
    float nM = 0.99f * emaM[k] + 0.01f * ws[W_CNT + k];
    red[k] = nM;
    __syncthreads();
    for (int s = 256; s >= 1; s >>= 1) {
        if (k < s) red[k] += red[k + s];
        __syncthreads();
    }
    float Ntot = red[0];
    float sm = (nM + 1e-5f) / (Ntot + 1e-5f * (float)KCODES) * Ntot;
    ws[W_NEWM + k] = sm;
    out[O_MM + k] = sm;
    if (k == 0) out[O_LOSS] = 0.25f * ws[W_LOSS] / (float)((size_t)NPTS * DIM);
}

__global__ void finalizeB(const float* __restrict__ emam,
                          float* __restrict__ out, const float* __restrict__ ws)
{
    int i = blockIdx.x * blockDim.x + threadIdx.x;  // 0..32767
    int k = i >> 6;
    float nm = 0.99f * emam[i] + 0.01f * ws[W_DM + i];
    out[O_M + i] = nm;
    out[O_EMB + i] = nm / ws[W_NEWM + k];
}

extern "C" void kernel_launch(void* const* d_in, const int* in_sizes, int n_in,
                              void* d_out, int out_size, void* d_ws, size_t ws_size,
                              hipStream_t stream)
{
    const float* enc  = (const float*)d_in[0];
    const float* emb  = (const float*)d_in[1];
    const float* emam = (const float*)d_in[2];
    const float* emaM = (const float*)d_in[3];
    float* out = (float*)d_out;
    float* ws  = (float*)d_ws;

    hipMemsetAsync(ws, 0, (size_t)W_TOTAL * sizeof(float), stream);
    cnorm_kernel<<<2, 256, 0, stream>>>(emb, ws);
    assign_kernel<<<NPTS/256, 256, 0, stream>>>(enc, emb, out, ws);
    scatter_kernel<<<64, 256, 0, stream>>>(enc, out, ws);
    finalizeA<<<1, 512, 0, stream>>>(emaM, out, ws);
    finalizeB<<<(KCODES*DIM)/256, 256, 0, stream>>>(emam, out, ws);
}

// Round 5
// 506.736 us; speedup vs baseline: 1.0137x; 1.0137x over previous
//
#include <hip/hip_runtime.h>

#define KCODES 512
#define DIM 64
#define NB 32
#define NH 64
#define NW 64
#define NPTS (NB*NH*NW)     // 131072
#define HW (NH*NW)          // 4096

// ---- output layout (floats) ----
#define O_OUT  0
#define O_LOSS 8388608
#define O_IDX  8388609
#define O_EMB  8519681
#define O_M    8552449
#define O_MM   8585217

// ---- workspace layout (floats) ----
#define W_DM   0
#define W_CNT  (KCODES*DIM)
#define W_LOSS (W_CNT + KCODES)
#define W_C    (W_LOSS + 1)
#define W_NEWM (W_C + KCODES)
#define W_TOTAL (W_NEWM + KCODES)

__global__ void cnorm_kernel(const float* __restrict__ emb, float* __restrict__ ws) {
    int k = blockIdx.x * blockDim.x + threadIdx.x;
    if (k >= KCODES) return;
    float s = 0.f;
    #pragma unroll
    for (int d = 0; d < DIM; ++d) { float v = emb[k*DIM + d]; s += v*v; }
    ws[W_C + k] = s;
}

// x held in 16 NAMED float4s (rounds 1-4: x[64] array was scratch-allocated,
// VGPR_Count 64-68 proves it). Dist operands via wave-uniform global reads
// (scalar path) -- no LDS in the hot loop (round-4 was ds_read-issue-bound:
// 8 waves x 16 b128 x 12cyc = 328us, exactly the measured time).
#define LOADX(q) float4 X##q = make_float4(px[(4*(q)+0)*(size_t)HW], \
    px[(4*(q)+1)*(size_t)HW], px[(4*(q)+2)*(size_t)HW], px[(4*(q)+3)*(size_t)HW]);
#define FMA4(q) { float4 e = er[q]; \
    a0 += X##q.x*e.x; a1 += X##q.y*e.y; a2 += X##q.z*e.z; a3 += X##q.w*e.w; }
#define QI(c,i,xv) { float q_ = T[wv][w][i]; \
    po[(size_t)((c)*16+(i))*HW] = q_; \
    float d_ = q_ - (xv); lsum = fmaf(d_, d_, lsum); }
#define EPI_CHUNK(c, Xa, Xb, Xc_, Xd_) { \
    _Pragma("unroll") \
    for (int jj = 0; jj < 16; ++jj) { \
        int p = jj*4 + pg; int kb = __shfl(bidx, p, 64); \
        T[wv][p][dl] = emb[kb*64 + (c)*16 + dl]; } \
    QI(c,0,Xa.x) QI(c,1,Xa.y) QI(c,2,Xa.z) QI(c,3,Xa.w) \
    QI(c,4,Xb.x) QI(c,5,Xb.y) QI(c,6,Xb.z) QI(c,7,Xb.w) \
    QI(c,8,Xc_.x) QI(c,9,Xc_.y) QI(c,10,Xc_.z) QI(c,11,Xc_.w) \
    QI(c,12,Xd_.x) QI(c,13,Xd_.y) QI(c,14,Xd_.z) QI(c,15,Xd_.w) }

__global__ __launch_bounds__(256, 2) void assign_kernel(
    const float* __restrict__ enc, const float* __restrict__ emb,
    const float* __restrict__ cns, float* __restrict__ out, float* __restrict__ ws)
{
    __shared__ float T[4][64][17];    // per-wave tile only (wave-lockstep use)
    const int t = threadIdx.x;
    const int w = t & 63;
    const int wv = t >> 6;
    const int R = blockIdx.x * 4 + wv;
    const int b = R >> 6, h = R & 63;

    const float* px = enc + (size_t)b * DIM * HW + h * NW + w;
    LOADX(0) LOADX(1) LOADX(2) LOADX(3) LOADX(4) LOADX(5) LOADX(6) LOADX(7)
    LOADX(8) LOADX(9) LOADX(10) LOADX(11) LOADX(12) LOADX(13) LOADX(14) LOADX(15)

    // ---- distance phase: bit-identical score math to rounds 1-4 ----
    float best = 3.402823466e38f;
    int bidx = 0;
    #pragma unroll 2
    for (int kk = 0; kk < KCODES; ++kk) {
        const float4* er = (const float4*)(emb + kk * DIM);   // uniform addr
        float cn = cns[kk];                                   // uniform addr
        float a0 = 0.f, a1 = 0.f, a2 = 0.f, a3 = 0.f;
        FMA4(0) FMA4(1) FMA4(2) FMA4(3) FMA4(4) FMA4(5) FMA4(6) FMA4(7)
        FMA4(8) FMA4(9) FMA4(10) FMA4(11) FMA4(12) FMA4(13) FMA4(14) FMA4(15)
        float score = cn - 2.f*((a0+a1)+(a2+a3));
        if (score < best) { best = score; bidx = kk; }  // strict < = first-min
    }

    // ---- epilogue: coalesced quantized gather via per-wave tile ----
    float* po = out + O_OUT + (size_t)b * DIM * HW + h * NW + w;
    const int pg = w >> 4;
    const int dl = w & 15;
    float lsum = 0.f;

    EPI_CHUNK(0, X0, X1, X2, X3)
    EPI_CHUNK(1, X4, X5, X6, X7)
    EPI_CHUNK(2, X8, X9, X10, X11)
    EPI_CHUNK(3, X12, X13, X14, X15)

    out[O_IDX + (size_t)R*64 + w] = (float)bidx;

    #pragma unroll
    for (int off = 32; off >= 1; off >>= 1) lsum += __shfl_down(lsum, off, 64);
    if (w == 0) atomicAdd(&ws[W_LOSS], lsum);
}

// Per-block LDS accumulation of dm/counts; no per-thread arrays (streams enc
// through the wave tile), then one coalesced 64-lane global atomic per row.
__global__ __launch_bounds__(256, 1) void scatter_kernel(
    const float* __restrict__ enc, const float* __restrict__ out,
    float* __restrict__ ws)
{
    __shared__ float dmL[KCODES][65];
    __shared__ float cntL[KCODES];
    __shared__ float T[4][64][17];
    const int t = threadIdx.x;
    const int w = t & 63;
    const int wv = t >> 6;
    const int pg = w >> 4, dl = w & 15;

    float* dmf = &dmL[0][0];
    for (int i = t; i < KCODES*65; i += 256) dmf[i] = 0.f;
    for (int i = t; i < KCODES; i += 256) cntL[i] = 0.f;
    __syncthreads();

    for (int r = 0; r < 8; ++r) {
        const int R = blockIdx.x * 32 + r*4 + wv;
        const int b = R >> 6, h = R & 63;
        const float* px = enc + (size_t)b * DIM * HW + h * NW + w;
        int bidx = (int)out[O_IDX + (size_t)R*64 + w];
        atomicAdd(&cntL[bidx], 1.0f);

        #pragma unroll
        for (int c = 0; c < 4; ++c) {
            #pragma unroll
            for (int i = 0; i < 16; ++i)
                T[wv][w][i] = px[(size_t)(c*16 + i) * HW];   // coalesced
            #pragma unroll
            for (int jj = 0; jj < 16; ++jj) {   // same-codeword lanes hit
                int p = jj*4 + pg;              // DIFFERENT dims -> no
                int kb = __shfl(bidx, p, 64);   // same-address serialization
                atomicAdd(&dmL[kb][c*16 + dl], T[wv][p][dl]);
            }
        }
    }
    __syncthreads();

    for (int k = wv*128; k < wv*128 + 128; ++k) {
        float c = cntL[k];
        if (c == 0.f) continue;                  // wave-uniform branch
        atomicAdd(&ws[W_DM + k*64 + w], dmL[k][w]);
        if (w == 0) atomicAdd(&ws[W_CNT + k], c);
    }
}

__global__ void finalizeA(const float* __restrict__ emaM,
                          float* __restrict__ out, float* __restrict__ ws)
{
    __shared__ float red[512];
    int k = threadIdx.x;
    float nM = 0.99f * emaM[k] + 0.01f * ws[W_CNT + k];
    red[k] = nM;
    __syncthreads();
    for (int s = 256; s >= 1; s >>= 1) {
        if (k < s) red[k] += red[k + s];
        __syncthreads();
    }
    float Ntot = red[0];
    float sm = (nM + 1e-5f) / (Ntot + 1e-5f * (float)KCODES) * Ntot;
    ws[W_NEWM + k] = sm;
    out[O_MM + k] = sm;
    if (k == 0) out[O_LOSS] = 0.25f * ws[W_LOSS] / (float)((size_t)NPTS * DIM);
}

__global__ void finalizeB(const float* __restrict__ emam,
                          float* __restrict__ out, const float* __restrict__ ws)
{
    int i = blockIdx.x * blockDim.x + threadIdx.x;
    int k = i >> 6;
    float nm = 0.99f * emam[i] + 0.01f * ws[W_DM + i];
    out[O_M + i] = nm;
    out[O_EMB + i] = nm / ws[W_NEWM + k];
}

extern "C" void kernel_launch(void* const* d_in, const int* in_sizes, int n_in,
                              void* d_out, int out_size, void* d_ws, size_t ws_size,
                              hipStream_t stream)
{
    const float* enc  = (const float*)d_in[0];
    const float* emb  = (const float*)d_in[1];
    const float* emam = (const float*)d_in[2];
    const float* emaM = (const float*)d_in[3];
    float* out = (float*)d_out;
    float* ws  = (float*)d_ws;

    hipMemsetAsync(ws, 0, (size_t)W_TOTAL * sizeof(float), stream);
    cnorm_kernel<<<2, 256, 0, stream>>>(emb, ws);
    assign_kernel<<<NPTS/256, 256, 0, stream>>>(enc, emb, ws + W_C, out, ws);
    scatter_kernel<<<64, 256, 0, stream>>>(enc, out, ws);
    finalizeA<<<1, 512, 0, stream>>>(emaM, out, ws);
    finalizeB<<<(KCODES*DIM)/256, 256, 0, stream>>>(emam, out, ws);
}

// Round 6
// 277.225 us; speedup vs baseline: 1.8528x; 1.8279x over previous
//
#include <hip/hip_runtime.h>

#define KCODES 512
#define DIM 64
#define NB 32
#define NH 64
#define NW 64
#define NPTS (NB*NH*NW)     // 131072
#define HW (NH*NW)          // 4096

// ---- output layout (floats) ----
#define O_OUT  0
#define O_LOSS 8388608
#define O_IDX  8388609
#define O_EMB  8519681
#define O_M    8552449
#define O_MM   8585217

// ---- workspace layout (floats) ----
#define W_DM   0
#define W_CNT  (KCODES*DIM)
#define W_LOSS (W_CNT + KCODES)
#define W_C    (W_LOSS + 1)
#define W_NEWM (W_C + KCODES)
#define W_TOTAL (W_NEWM + KCODES)

#define XPAD 68   // bank-audited: frag reads <=2-way with the p/k mappings below
#define EPAD 68

__global__ void cnorm_kernel(const float* __restrict__ emb, float* __restrict__ ws) {
    int k = blockIdx.x * blockDim.x + threadIdx.x;
    if (k >= KCODES) return;
    float s = 0.f;
    #pragma unroll
    for (int d = 0; d < DIM; ++d) { float v = emb[k*DIM + d]; s += v*v; }
    ws[W_C + k] = s;
}

// Register-tiled fp32 GEMM: block = 128 points x 512 codewords, thread =
// 8x8 micro-tile (acc[8][8] static-indexed -> stays in VGPRs; no thread
// ever holds a full 64-dim x vector: rounds 1-5's scratch trap).
// Per d4-chunk: 16 ds_read_b128 : 256 FMA = 1:16 -> LDS-issue ~82us model.
__global__ __launch_bounds__(256, 2) void assign_kernel(
    const float* __restrict__ enc, const float* __restrict__ emb,
    float* __restrict__ out, float* __restrict__ ws)
{
    __shared__ float XL[128*XPAD];   // [point][d]
    __shared__ float EL[128*EPAD];   // [cw][d], aliased as T2 in epilogue
    __shared__ float cnT[128];
    __shared__ int   bestI[128];

    const int t  = threadIdx.x;
    const int tx = t & 15;           // codeword-lane (argmin reduce axis)
    const int ty = t >> 4;           // point-group

    // ---- stage X: rows R0,R0+1 (64 w-points x 64 dims each), transposed ----
    const int R0 = blockIdx.x * 2;
    #pragma unroll
    for (int r2 = 0; r2 < 2; ++r2) {
        int R = R0 + r2, b = R >> 6, h = R & 63;
        const float* base = enc + ((size_t)b*64)*HW + (size_t)h*64;
        #pragma unroll
        for (int it = 0; it < 4; ++it) {
            int d = it*16 + ty;
            float4 v = *(const float4*)(base + (size_t)d*HW + tx*4);
            int p0 = r2*64 + tx*4;
            XL[(p0+0)*XPAD + d] = v.x;
            XL[(p0+1)*XPAD + d] = v.y;
            XL[(p0+2)*XPAD + d] = v.z;
            XL[(p0+3)*XPAD + d] = v.w;
        }
    }

    float best[8]; int bidx[8];
    #pragma unroll
    for (int i = 0; i < 8; ++i) { best[i] = 3.402823466e38f; bidx[i] = 0; }

    for (int tile = 0; tile < 4; ++tile) {
        __syncthreads();             // prior tile's EL reads done
        // stage E tile: 128 cw x 64 d (emb already [k][d])
        const float* esrc = emb + (size_t)tile*128*64;
        #pragma unroll
        for (int it = 0; it < 8; ++it) {
            int idx = t + it*256;            // float4 index 0..2047
            int row = idx >> 4;
            int col = (idx & 15)*4;
            float4 v = *(const float4*)(esrc + row*64 + col);
            *(float4*)(&EL[row*EPAD + col]) = v;
        }
        if (t < 128) cnT[t] = ws[W_C + tile*128 + t];  // scalar (W_C not 16B-aligned)
        __syncthreads();

        float acc[8][8];
        #pragma unroll
        for (int i = 0; i < 8; ++i)
            #pragma unroll
            for (int j = 0; j < 8; ++j) acc[i][j] = 0.f;

        for (int c = 0; c < 16; ++c) {       // d-chunks of 4
            float4 xf[8], ef[8];
            #pragma unroll
            for (int i = 0; i < 8; ++i) {    // p-mapping: per-wave disjoint bank windows
                int p = 2*ty + (i&1) + 32*(i>>1);
                xf[i] = *(const float4*)(&XL[p*XPAD + c*4]);
            }
            #pragma unroll
            for (int j = 0; j < 8; ++j) {    // k rows step 1 in tx -> <=2-way
                int r = tx + 16*j;
                ef[j] = *(const float4*)(&EL[r*EPAD + c*4]);
            }
            #pragma unroll
            for (int i = 0; i < 8; ++i)
                #pragma unroll
                for (int j = 0; j < 8; ++j) {
                    acc[i][j] = fmaf(xf[i].x, ef[j].x, acc[i][j]);
                    acc[i][j] = fmaf(xf[i].y, ef[j].y, acc[i][j]);
                    acc[i][j] = fmaf(xf[i].z, ef[j].z, acc[i][j]);
                    acc[i][j] = fmaf(xf[i].w, ef[j].w, acc[i][j]);
                }
        }

        #pragma unroll
        for (int j = 0; j < 8; ++j) {
            int k = tile*128 + tx + 16*j;
            float cn = cnT[tx + 16*j];
            #pragma unroll
            for (int i = 0; i < 8; ++i) {
                float s = cn - 2.f*acc[i][j];
                // order-independent first-min: strict < plus index tie-break
                if (s < best[i] || (s == best[i] && k < bidx[i])) { best[i] = s; bidx[i] = k; }
            }
        }
    }

    // ---- cross-lane argmin over the 16 tx-lanes sharing each point ----
    #pragma unroll
    for (int i = 0; i < 8; ++i) {
        float b = best[i]; int kx = bidx[i];
        #pragma unroll
        for (int off = 1; off < 16; off <<= 1) {
            float ob = __shfl_xor(b, off, 64);
            int   ok = __shfl_xor(kx, off, 64);
            if (ob < b || (ob == b && ok < kx)) { b = ob; kx = ok; }
        }
        if (tx == 0) bestI[2*ty + (i&1) + 32*(i>>1)] = kx;
    }
    __syncthreads();

    if (t < 128) out[O_IDX + (size_t)R0*64 + t] = (float)bestI[t];

    // ---- epilogue: quantized gather via wave tile (T2 aliases EL) ----
    float (*T2)[64][17] = (float(*)[64][17])EL;
    const int wv = t >> 6, w = t & 63;
    const int row = wv & 1, dhalf = wv >> 1;   // wave -> (point-row, dim-half)
    const int pg = w >> 4, dl = w & 15;
    const int R = R0 + row, bb = R >> 6, hh = R & 63;
    float* po = out + O_OUT + ((size_t)bb*64)*HW + (size_t)hh*64 + w;
    float lsum = 0.f;

    #pragma unroll
    for (int c2 = 0; c2 < 2; ++c2) {
        int c = dhalf*2 + c2;
        #pragma unroll
        for (int jj = 0; jj < 16; ++jj) {      // 4 points x 16 contiguous dims
            int p16 = jj*4 + pg;
            int kb = bestI[row*64 + p16];
            T2[wv][p16][dl] = emb[kb*64 + c*16 + dl];
        }
        #pragma unroll
        for (int i = 0; i < 16; ++i) {         // wave-lockstep un-transpose
            int d = c*16 + i;
            float q = T2[wv][w][i];
            po[(size_t)d*HW] = q;
            float df = q - XL[(row*64 + w)*XPAD + d];
            lsum = fmaf(df, df, lsum);
        }
    }
    #pragma unroll
    for (int off = 32; off >= 1; off >>= 1) lsum += __shfl_down(lsum, off, 64);
    if (w == 0) atomicAdd(&ws[W_LOSS], lsum);
}

// 256 blocks (1/CU at 152KB LDS), 512 points each: per-block LDS dm/cnt
// accumulation, one coalesced 64-lane global atomic per nonzero row.
__global__ __launch_bounds__(256, 1) void scatter_kernel(
    const float* __restrict__ enc, const float* __restrict__ out,
    float* __restrict__ ws)
{
    __shared__ float dmL[KCODES][65];
    __shared__ float cntL[KCODES];
    __shared__ float T[4][64][17];
    const int t = threadIdx.x;
    const int w = t & 63;
    const int wv = t >> 6;
    const int pg = w >> 4, dl = w & 15;

    float* dmf = &dmL[0][0];
    for (int i = t; i < KCODES*65; i += 256) dmf[i] = 0.f;
    for (int i = t; i < KCODES; i += 256) cntL[i] = 0.f;
    __syncthreads();

    for (int r = 0; r < 2; ++r) {
        const int R = blockIdx.x * 8 + r*4 + wv;
        const int b = R >> 6, h = R & 63;
        const float* px = enc + (size_t)b * DIM * HW + (size_t)h * NW + w;
        int bidx = (int)out[O_IDX + (size_t)R*64 + w];
        atomicAdd(&cntL[bidx], 1.0f);

        #pragma unroll
        for (int c = 0; c < 4; ++c) {
            #pragma unroll
            for (int i = 0; i < 16; ++i)
                T[wv][w][i] = px[(size_t)(c*16 + i) * HW];   // coalesced
            #pragma unroll
            for (int jj = 0; jj < 16; ++jj) {   // same-codeword lanes hit
                int p = jj*4 + pg;              // DIFFERENT dims -> no
                int kb = __shfl(bidx, p, 64);   // same-address serialization
                atomicAdd(&dmL[kb][c*16 + dl], T[wv][p][dl]);
            }
        }
    }
    __syncthreads();

    for (int k = wv*128; k < wv*128 + 128; ++k) {
        float c = cntL[k];
        if (c == 0.f) continue;                  // wave-uniform branch
        atomicAdd(&ws[W_DM + k*64 + w], dmL[k][w]);
        if (w == 0) atomicAdd(&ws[W_CNT + k], c);
    }
}

__global__ void finalizeA(const float* __restrict__ emaM,
                          float* __restrict__ out, float* __restrict__ ws)
{
    __shared__ float red[512];
    int k = threadIdx.x;
    float nM = 0.99f * emaM[k] + 0.01f * ws[W_CNT + k];
    red[k] = nM;
    __syncthreads();
    for (int s = 256; s >= 1; s >>= 1) {
        if (k < s) red[k] += red[k + s];
        __syncthreads();
    }
    float Ntot = red[0];
    float sm = (nM + 1e-5f) / (Ntot + 1e-5f * (float)KCODES) * Ntot;
    ws[W_NEWM + k] = sm;
    out[O_MM + k] = sm;
    if (k == 0) out[O_LOSS] = 0.25f * ws[W_LOSS] / (float)((size_t)NPTS * DIM);
}

__global__ void finalizeB(const float* __restrict__ emam,
                          float* __restrict__ out, const float* __restrict__ ws)
{
    int i = blockIdx.x * blockDim.x + threadIdx.x;
    int k = i >> 6;
    float nm = 0.99f * emam[i] + 0.01f * ws[W_DM + i];
    out[O_M + i] = nm;
    out[O_EMB + i] = nm / ws[W_NEWM + k];
}

extern "C" void kernel_launch(void* const* d_in, const int* in_sizes, int n_in,
                              void* d_out, int out_size, void* d_ws, size_t ws_size,
                              hipStream_t stream)
{
    const float* enc  = (const float*)d_in[0];
    const float* emb  = (const float*)d_in[1];
    const float* emam = (const float*)d_in[2];
    const float* emaM = (const float*)d_in[3];
    float* out = (float*)d_out;
    float* ws  = (float*)d_ws;

    hipMemsetAsync(ws, 0, (size_t)W_TOTAL * sizeof(float), stream);
    cnorm_kernel<<<2, 256, 0, stream>>>(emb, ws);
    assign_kernel<<<NPTS/128, 256, 0, stream>>>(enc, emb, out, ws);   // 1024 blocks
    scatter_kernel<<<256, 256, 0, stream>>>(enc, out, ws);
    finalizeA<<<1, 512, 0, stream>>>(emaM, out, ws);
    finalizeB<<<(KCODES*DIM)/256, 256, 0, stream>>>(emam, out, ws);
}